// Round 1
// baseline (2002.690 us; speedup 1.0000x reference)
//
#include <hip/hip_runtime.h>
#include <math.h>

#define SB 4
#define SS 2048
#define SD 1024
#define SH 16
#define KTOP 409   // max(2048//5, 1)

// ---------------- K1: fused Q/K projection GEMM (fp32, 128x128 tile, BK=16) ----
// grid (N/128=8, M/128=16, 2)  z: 0 -> Q, 1 -> K
__global__ __launch_bounds__(256) void gemm_qk(
    const float* __restrict__ xq, const float* __restrict__ wq,
    const float* __restrict__ bq, float* __restrict__ Qo,
    const float* __restrict__ xk, const float* __restrict__ wk,
    const float* __restrict__ bk, float* __restrict__ Ko)
{
  const float *A, *Bm, *bias; float* C;
  if (blockIdx.z == 0) { A = xq; Bm = wq; bias = bq; C = Qo; }
  else                 { A = xk; Bm = wk; bias = bk; C = Ko; }
  const int n0 = blockIdx.x * 128;
  const int m0 = blockIdx.y * 128;
  __shared__ __align__(16) float As[16 * 128];
  __shared__ __align__(16) float Bs[16 * 128];
  const int tid = threadIdx.x;
  const int tx = tid & 15, ty = tid >> 4;
  float acc[8][8];
#pragma unroll
  for (int i = 0; i < 8; ++i)
#pragma unroll
    for (int j = 0; j < 8; ++j) acc[i][j] = 0.f;

  for (int k0 = 0; k0 < SD; k0 += 16) {
    __syncthreads();
#pragma unroll
    for (int l = 0; l < 2; ++l) {
      int f = tid + l * 256;
      int row = f >> 2, k4 = (f & 3) << 2;
      float4 av = *(const float4*)&A[(size_t)(m0 + row) * SD + k0 + k4];
      As[(k4 + 0) * 128 + row] = av.x;
      As[(k4 + 1) * 128 + row] = av.y;
      As[(k4 + 2) * 128 + row] = av.z;
      As[(k4 + 3) * 128 + row] = av.w;
      int kk = f >> 5, n4 = (f & 31) << 2;
      *(float4*)&Bs[kk * 128 + n4] =
          *(const float4*)&Bm[(size_t)(k0 + kk) * SD + n0 + n4];
    }
    __syncthreads();
#pragma unroll 4
    for (int k = 0; k < 16; ++k) {
      float4 a0 = *(const float4*)&As[k * 128 + ty * 8];
      float4 a1 = *(const float4*)&As[k * 128 + ty * 8 + 4];
      float4 b0 = *(const float4*)&Bs[k * 128 + tx * 4];
      float4 b1 = *(const float4*)&Bs[k * 128 + 64 + tx * 4];
      float ar[8] = {a0.x, a0.y, a0.z, a0.w, a1.x, a1.y, a1.z, a1.w};
      float br[8] = {b0.x, b0.y, b0.z, b0.w, b1.x, b1.y, b1.z, b1.w};
#pragma unroll
      for (int i = 0; i < 8; ++i)
#pragma unroll
        for (int j = 0; j < 8; ++j) acc[i][j] += ar[i] * br[j];
    }
  }
  float4 ba = *(const float4*)&bias[n0 + tx * 4];
  float4 bb = *(const float4*)&bias[n0 + 64 + tx * 4];
#pragma unroll
  for (int i = 0; i < 8; ++i) {
    int row = m0 + ty * 8 + i;
    float4 c0 = make_float4(acc[i][0] + ba.x, acc[i][1] + ba.y,
                            acc[i][2] + ba.z, acc[i][3] + ba.w);
    float4 c1 = make_float4(acc[i][4] + bb.x, acc[i][5] + bb.y,
                            acc[i][6] + bb.z, acc[i][7] + bb.w);
    *(float4*)&C[(size_t)row * SD + n0 + tx * 4] = c0;
    *(float4*)&C[(size_t)row * SD + n0 + 64 + tx * 4] = c1;
  }
}

// ---------------- K2: Gram tile + fused circular-diagonal reduction ------------
// per batch b: grid (16 u-tiles, 16 t-tiles, 16 heads). mcb = mean_corr + b*H*S
__global__ __launch_bounds__(256) void corr_k(
    const float* __restrict__ Qb, const float* __restrict__ Kb,
    float* __restrict__ mcb)
{
  const int h  = blockIdx.z;
  const int u0 = blockIdx.x * 128;
  const int t0 = blockIdx.y * 128;
  __shared__ __align__(16) float lds[16384];   // Qs[64][128] | Ks[64][128]
  float* Qs = lds;
  float* Ks = lds + 8192;
  const int tid = threadIdx.x;
  const int tx = tid & 15, ty = tid >> 4;

#pragma unroll
  for (int l = 0; l < 8; ++l) {
    int f = tid + l * 256;
    int t = f >> 4, d4 = (f & 15) << 2;
    float4 qv = *(const float4*)&Qb[(size_t)(t0 + t) * SD + h * 64 + d4];
    Qs[(d4 + 0) * 128 + t] = qv.x;
    Qs[(d4 + 1) * 128 + t] = qv.y;
    Qs[(d4 + 2) * 128 + t] = qv.z;
    Qs[(d4 + 3) * 128 + t] = qv.w;
    float4 kv = *(const float4*)&Kb[(size_t)(u0 + t) * SD + h * 64 + d4];
    Ks[(d4 + 0) * 128 + t] = kv.x;
    Ks[(d4 + 1) * 128 + t] = kv.y;
    Ks[(d4 + 2) * 128 + t] = kv.z;
    Ks[(d4 + 3) * 128 + t] = kv.w;
  }
  __syncthreads();

  float acc[8][8];
#pragma unroll
  for (int i = 0; i < 8; ++i)
#pragma unroll
    for (int j = 0; j < 8; ++j) acc[i][j] = 0.f;

#pragma unroll 4
  for (int d = 0; d < 64; ++d) {
    float4 a0 = *(const float4*)&Qs[d * 128 + ty * 8];
    float4 a1 = *(const float4*)&Qs[d * 128 + ty * 8 + 4];
    float4 b0 = *(const float4*)&Ks[d * 128 + tx * 4];
    float4 b1 = *(const float4*)&Ks[d * 128 + 64 + tx * 4];
    float ar[8] = {a0.x, a0.y, a0.z, a0.w, a1.x, a1.y, a1.z, a1.w};
    float br[8] = {b0.x, b0.y, b0.z, b0.w, b1.x, b1.y, b1.z, b1.w};
#pragma unroll
    for (int i = 0; i < 8; ++i)
#pragma unroll
      for (int j = 0; j < 8; ++j) acc[i][j] += ar[i] * br[j];
  }

  // rows: t = t0 + ty*8 + i ; cols: u = u0 + tx*4 + j' + 64*e  (e = j>=4)
  // in-thread pre-reduction into 22 diagonal buckets
  float diag[2][11];
#pragma unroll
  for (int e = 0; e < 2; ++e)
#pragma unroll
    for (int dd = 0; dd < 11; ++dd) diag[e][dd] = 0.f;
#pragma unroll
  for (int i = 0; i < 8; ++i)
#pragma unroll
    for (int j = 0; j < 8; ++j) diag[j >> 2][i - (j & 3) + 3] += acc[i][j];

  __syncthreads();
  if (tid < 255) lds[tid] = 0.f;   // 255 diagonal bins, reuse LDS
  __syncthreads();
  const int basei = 8 * ty - 4 * tx + 127;
#pragma unroll
  for (int e = 0; e < 2; ++e)
#pragma unroll
    for (int dd = 0; dd < 11; ++dd)
      atomicAdd(&lds[basei - 64 * e + dd - 3], diag[e][dd]);
  __syncthreads();
  if (tid < 255) {
    int tau = (t0 - u0 + tid - 127) & (SS - 1);
    atomicAdd(&mcb[h * SS + tau], lds[tid]);
  }
}

// ---------------- K3: radix-select top-409 + softmax per (b,h) -----------------
__global__ __launch_bounds__(256) void topk_k(
    const float* __restrict__ mc, int* __restrict__ sidx, float* __restrict__ sw)
{
  const int bh = blockIdx.x;
  __shared__ float vals[SS];
  __shared__ unsigned int keys[SS];
  __shared__ int el_i[KTOP];
  __shared__ float el_w[KTOP];
  __shared__ int icnt, cnt2;
  __shared__ unsigned int kmax_sh;
  __shared__ float Zsh;
  const int tid = threadIdx.x;
  const float scale = 1.0f / 512.0f;   // 1/(dh * sqrt(dh))

  for (int l = 0; l < 8; ++l) {
    int i = tid + l * 256;
    float v = mc[bh * SS + i] * scale;
    vals[i] = v;
    unsigned int u = __float_as_uint(v);
    keys[i] = (u & 0x80000000u) ? ~u : (u | 0x80000000u);
  }
  if (tid == 0) { kmax_sh = 0u; cnt2 = 0; Zsh = 0.f; }
  __syncthreads();

  unsigned int lm = 0u;
  for (int l = 0; l < 8; ++l) lm = max(lm, keys[tid + l * 256]);
  atomicMax(&kmax_sh, lm);

  unsigned int prefix = 0u;
  for (int bit = 31; bit >= 0; --bit) {
    unsigned int cand = prefix | (1u << bit);
    int c = 0;
    for (int l = 0; l < 8; ++l) c += (keys[tid + l * 256] >= cand) ? 1 : 0;
    __syncthreads();
    if (tid == 0) icnt = 0;
    __syncthreads();
    atomicAdd(&icnt, c);
    __syncthreads();
    if (icnt >= KTOP) prefix = cand;   // uniform across block
  }
  const unsigned int T = prefix;       // exact 409th-largest key
  __syncthreads();
  unsigned int km = kmax_sh;
  float vmax = __uint_as_float((km & 0x80000000u) ? (km ^ 0x80000000u) : ~km);

  // compact strictly-greater elements (order irrelevant downstream)
  for (int l = 0; l < 8; ++l) {
    int i = tid + l * 256;
    if (keys[i] > T) {
      int pos = atomicAdd(&cnt2, 1);
      el_i[pos] = i;
      el_w[pos] = expf(vals[i] - vmax);
    }
  }
  __syncthreads();
  if (tid == 0) {   // fill remaining slots with ==T, lowest index first (jax tie rule)
    int pos = cnt2;
    for (int i = 0; i < SS && pos < KTOP; ++i)
      if (keys[i] == T) { el_i[pos] = i; el_w[pos] = expf(vals[i] - vmax); ++pos; }
  }
  __syncthreads();
  float z = 0.f;
  for (int l = tid; l < KTOP; l += 256) z += el_w[l];
  atomicAdd(&Zsh, z);
  __syncthreads();
  float invZ = 1.0f / Zsh;
  for (int l = tid; l < KTOP; l += 256) {
    sidx[bh * KTOP + l] = el_i[l];
    sw[bh * KTOP + l]   = el_w[l] * invZ;
  }
}

// ---------------- K4: xbar[b,h,:] = sum_sel w * xv[b,idx,:] --------------------
__global__ __launch_bounds__(256) void xbar_k(
    const int* __restrict__ sidx, const float* __restrict__ sw,
    const float* __restrict__ xv, float* __restrict__ xbar)
{
  const int bh = blockIdx.x, b = bh >> 4;
  __shared__ int il[KTOP];
  __shared__ float wl[KTOP];
  const int tid = threadIdx.x;
  for (int l = tid; l < KTOP; l += 256) { il[l] = sidx[bh * KTOP + l]; wl[l] = sw[bh * KTOP + l]; }
  __syncthreads();
  const float4* xv4 = (const float4*)xv;
  float4 acc = make_float4(0.f, 0.f, 0.f, 0.f);
  for (int r = 0; r < KTOP; ++r) {
    float w = wl[r];
    float4 v = xv4[(size_t)(b * SS + il[r]) * 256 + tid];
    acc.x += w * v.x; acc.y += w * v.y; acc.z += w * v.z; acc.w += w * v.w;
  }
  ((float4*)xbar)[(size_t)bh * 256 + tid] = acc;
}

// ---------------- K5a: init attended=bv, outrow=bo -----------------------------
__global__ __launch_bounds__(256) void initbias_k(
    const float* __restrict__ bv, const float* __restrict__ bo,
    float* __restrict__ att, float* __restrict__ orow)
{
  int i = blockIdx.x * 256 + threadIdx.x;   // < 8192
  if (i < 4096) att[i] = bv[i & 1023];
  else          orow[i - 4096] = bo[i & 1023];
}

// ---------------- K5: attended[b,j] += sum_i xbar[b,j/64,i]*wv[i,j] ------------
// grid (16 i-chunks, 4 b)
__global__ __launch_bounds__(256) void attend_k(
    const float* __restrict__ xbar, const float* __restrict__ wv,
    float* __restrict__ att)
{
  const int b = blockIdx.y, i0 = blockIdx.x * 64;
  __shared__ float xs[16 * 64];
  const int tid = threadIdx.x;
#pragma unroll
  for (int l = 0; l < 4; ++l) {
    int f = tid + l * 256;
    xs[f] = xbar[(size_t)(b * 16 + (f >> 6)) * 1024 + i0 + (f & 63)];
  }
  __syncthreads();
  const float4* wv4 = (const float4*)wv;
  const int h = tid >> 4;   // head of columns tid*4..tid*4+3
  float4 acc = make_float4(0.f, 0.f, 0.f, 0.f);
  for (int m = 0; m < 64; ++m) {
    float xvs = xs[h * 64 + m];
    float4 w = wv4[(size_t)(i0 + m) * 256 + tid];
    acc.x += xvs * w.x; acc.y += xvs * w.y; acc.z += xvs * w.z; acc.w += xvs * w.w;
  }
  float* dst = att + (size_t)b * 1024 + tid * 4;
  atomicAdd(dst + 0, acc.x); atomicAdd(dst + 1, acc.y);
  atomicAdd(dst + 2, acc.z); atomicAdd(dst + 3, acc.w);
}

// ---------------- K6: outrow[b,n] += sum_m att[b,m]*wo[m,n] --------------------
__global__ __launch_bounds__(256) void oproj_k(
    const float* __restrict__ att, const float* __restrict__ wo,
    float* __restrict__ orow)
{
  const int b = blockIdx.y, m0 = blockIdx.x * 64;
  __shared__ float as_[64];
  const int tid = threadIdx.x;
  if (tid < 64) as_[tid] = att[(size_t)b * 1024 + m0 + tid];
  __syncthreads();
  const float4* wo4 = (const float4*)wo;
  float4 acc = make_float4(0.f, 0.f, 0.f, 0.f);
  for (int m = 0; m < 64; ++m) {
    float a = as_[m];
    float4 w = wo4[(size_t)(m0 + m) * 256 + tid];
    acc.x += a * w.x; acc.y += a * w.y; acc.z += a * w.z; acc.w += a * w.w;
  }
  float* dst = orow + (size_t)b * 1024 + tid * 4;
  atomicAdd(dst + 0, acc.x); atomicAdd(dst + 1, acc.y);
  atomicAdd(dst + 2, acc.z); atomicAdd(dst + 3, acc.w);
}

// ---------------- K7: broadcast outrow across S --------------------------------
__global__ __launch_bounds__(256) void bcast_k(
    const float* __restrict__ orow, float* __restrict__ out)
{
  int idx = blockIdx.x * 256 + threadIdx.x;           // float4 index, < 2097152
  const float4* o4 = (const float4*)orow;
  ((float4*)out)[idx] = o4[((idx >> 19) << 8) | (idx & 255)];
}

extern "C" void kernel_launch(void* const* d_in, const int* in_sizes, int n_in,
                              void* d_out, int out_size, void* d_ws, size_t ws_size,
                              hipStream_t stream) {
  (void)in_sizes; (void)n_in; (void)out_size; (void)ws_size;
  const float* xq = (const float*)d_in[0];
  const float* xk = (const float*)d_in[1];
  const float* xv = (const float*)d_in[2];
  const float* wq = (const float*)d_in[3];
  const float* bq = (const float*)d_in[4];
  const float* wk = (const float*)d_in[5];
  const float* bk = (const float*)d_in[6];
  const float* wv = (const float*)d_in[7];
  const float* bv = (const float*)d_in[8];
  const float* wo = (const float*)d_in[9];
  const float* bo = (const float*)d_in[10];
  float* out = (float*)d_out;
  float* ws  = (float*)d_ws;

  // workspace layout (floats); total ~17.8 MB
  float* Qb   = ws;                       // S*D      = 2097152
  float* Kb   = ws + 2097152;             // S*D      = 2097152
  float* mc   = ws + 4194304;             // B*H*S    = 131072
  int*   sidx = (int*)(ws + 4325376);     // B*H*KTOP = 26176
  float* sw   = ws + 4351552;             // 26176
  float* xbar = ws + 4377728;             // B*H*D    = 65536
  float* att  = ws + 4443264;             // B*D      = 4096
  float* orow = ws + 4447360;             // B*D      = 4096

  hipMemsetAsync(mc, 0, (size_t)SB * SH * SS * sizeof(float), stream);
  for (int b = 0; b < SB; ++b) {
    gemm_qk<<<dim3(8, 16, 2), 256, 0, stream>>>(
        xq + (size_t)b * SS * SD, wq, bq, Qb,
        xk + (size_t)b * SS * SD, wk, bk, Kb);
    corr_k<<<dim3(16, 16, 16), 256, 0, stream>>>(Qb, Kb, mc + (size_t)b * SH * SS);
  }
  topk_k<<<dim3(SB * SH), 256, 0, stream>>>(mc, sidx, sw);
  xbar_k<<<dim3(SB * SH), 256, 0, stream>>>(sidx, sw, xv, xbar);
  initbias_k<<<dim3(32), 256, 0, stream>>>(bv, bo, att, orow);
  attend_k<<<dim3(16, SB), 256, 0, stream>>>(xbar, wv, att);
  oproj_k<<<dim3(16, SB), 256, 0, stream>>>(att, wo, orow);
  bcast_k<<<dim3(8192), 256, 0, stream>>>(orow, out);
}

// Round 3
// 1288.602 us; speedup vs baseline: 1.5542x; 1.5542x over previous
//
#include <hip/hip_runtime.h>
#include <math.h>

#define SB 4
#define SS 2048
#define SD 1024
#define SH 16
#define KTOP 409   // max(2048//5, 1)

typedef float f32x4  __attribute__((ext_vector_type(4)));
typedef short bf16x8 __attribute__((ext_vector_type(8)));
typedef short s16x4  __attribute__((ext_vector_type(4)));

__device__ __forceinline__ short f2bf(float x) {
  unsigned u = __float_as_uint(x);
  u += 0x7fff + ((u >> 16) & 1);           // RNE
  return (short)(u >> 16);
}
__device__ __forceinline__ float bf2f(short s) {
  return __uint_as_float(((unsigned)(unsigned short)s) << 16);
}

// ---------------- P0: transpose + split W[k][n] -> Wt[n][{hi:0..1023 | lo:1024..2047}]
__global__ __launch_bounds__(256) void splitwt_k(
    const float* __restrict__ wq, const float* __restrict__ wk,
    short* __restrict__ wqt, short* __restrict__ wkt)
{
  const float* W = blockIdx.z ? wk : wq;
  short* Wt = blockIdx.z ? wkt : wqt;
  const int n0 = blockIdx.x * 64, k0 = blockIdx.y * 64;
  __shared__ float T[64][65];
  const int tid = threadIdx.x;
#pragma unroll
  for (int l = 0; l < 4; ++l) {
    int idx = tid + l * 256;
    int r = idx >> 4, c4 = (idx & 15) << 2;
    float4 v = *(const float4*)&W[(size_t)(k0 + r) * SD + n0 + c4];
    T[r][c4 + 0] = v.x; T[r][c4 + 1] = v.y; T[r][c4 + 2] = v.z; T[r][c4 + 3] = v.w;
  }
  __syncthreads();
#pragma unroll
  for (int l = 0; l < 4; ++l) {
    int idx = tid + l * 256;
    int nr = idx >> 4, k4 = (idx & 15) << 2;
    s16x4 hi, lo;
#pragma unroll
    for (int j = 0; j < 4; ++j) {
      float x = T[k4 + j][nr];
      short hb = f2bf(x);
      hi[j] = hb; lo[j] = f2bf(x - bf2f(hb));
    }
    *(s16x4*)&Wt[(size_t)(n0 + nr) * 2048 + k0 + k4] = hi;
    *(s16x4*)&Wt[(size_t)(n0 + nr) * 2048 + 1024 + k0 + k4] = lo;
  }
}

// ---------------- P1: split X[m][k] fp32 -> Xs[m][{hi|lo}] bf16 ----------------
__global__ __launch_bounds__(256) void xsplit_k(
    const float* __restrict__ xq, const float* __restrict__ xk,
    short* __restrict__ Xqs, short* __restrict__ Xks)
{
  const float* X = blockIdx.z ? xk : xq;
  short* Xs = blockIdx.z ? Xks : Xqs;
  int f = blockIdx.x * 256 + threadIdx.x;      // float4 id, < 524288
  int m = f >> 8, k4 = (f & 255) << 2;
  float4 v = *(const float4*)&X[(size_t)m * SD + k4];
  float xs[4] = {v.x, v.y, v.z, v.w};
  s16x4 hi, lo;
#pragma unroll
  for (int j = 0; j < 4; ++j) {
    short hb = f2bf(xs[j]);
    hi[j] = hb; lo[j] = f2bf(xs[j] - bf2f(hb));
  }
  *(s16x4*)&Xs[(size_t)m * 2048 + k4] = hi;
  *(s16x4*)&Xs[(size_t)m * 2048 + 1024 + k4] = lo;
}

// ---------------- K1: split-bf16 MFMA projection GEMM (16x16x32) ---------------
// C = X @ W + bias via hi*hi + lo*hi + hi*lo. Tile 128m x 64n, BK=64,
// 4 waves stacked in m (32 rows each). Out[m][h*128 + d]=hi, +64=lo.
__global__ __launch_bounds__(256) void proj_k(
    const short* __restrict__ Xq, const short* __restrict__ Wq,
    const float* __restrict__ bq, short* __restrict__ Qs,
    const short* __restrict__ Xk, const short* __restrict__ Wk,
    const float* __restrict__ bk, short* __restrict__ Ks)
{
  const short *Xs, *Wt; const float* bias; short* Out;
  if (blockIdx.z == 0) { Xs = Xq; Wt = Wq; bias = bq; Out = Qs; }
  else                 { Xs = Xk; Wt = Wk; bias = bk; Out = Ks; }
  const int n0 = blockIdx.x * 64, m0 = blockIdx.y * 128;
  __shared__ __align__(16) short Ah[128 * 64];
  __shared__ __align__(16) short Al[128 * 64];
  __shared__ __align__(16) short Bs[64 * 64];
  const int tid = threadIdx.x;
  const int wave = tid >> 6, lane = tid & 63, l15 = lane & 15, kq = lane >> 4;
  f32x4 acc[2][4];
#pragma unroll
  for (int i = 0; i < 2; ++i)
#pragma unroll
    for (int j = 0; j < 4; ++j)
#pragma unroll
      for (int r = 0; r < 4; ++r) acc[i][j][r] = 0.f;
  float bval[4];
#pragma unroll
  for (int jn = 0; jn < 4; ++jn) bval[jn] = bias[n0 + jn * 16 + l15];

  for (int s = 0; s < 16; ++s) {
    __syncthreads();
    // stage A hi/lo (128x64)
#pragma unroll
    for (int l = 0; l < 4; ++l) {
      int idx = tid + l * 256;
      int row = idx >> 3, seg = idx & 7;
      size_t src = (size_t)(m0 + row) * 2048 + s * 64 + seg * 8;
      int dst = row * 64 + ((seg ^ (row & 7)) << 3);
      *(bf16x8*)&Ah[dst] = *(const bf16x8*)&Xs[src];
      *(bf16x8*)&Al[dst] = *(const bf16x8*)&Xs[src + 1024];
    }
    // stage B hi (64x64)
#pragma unroll
    for (int l = 0; l < 2; ++l) {
      int idx = tid + l * 256;
      int row = idx >> 3, seg = idx & 7;
      *(bf16x8*)&Bs[row * 64 + ((seg ^ (row & 7)) << 3)] =
          *(const bf16x8*)&Wt[(size_t)(n0 + row) * 2048 + s * 64 + seg * 8];
    }
    __syncthreads();
    // load A fragments (kept for lo-pass)
    bf16x8 ah[2][2], al[2][2];
#pragma unroll
    for (int i = 0; i < 2; ++i)
#pragma unroll
      for (int ks = 0; ks < 2; ++ks) {
        int ar = wave * 32 + i * 16 + l15;
        int seg = ks * 4 + kq;
        int addr = ar * 64 + ((seg ^ (ar & 7)) << 3);
        ah[i][ks] = *(const bf16x8*)&Ah[addr];
        al[i][ks] = *(const bf16x8*)&Al[addr];
      }
#pragma unroll
    for (int ks = 0; ks < 2; ++ks)
#pragma unroll
      for (int jn = 0; jn < 4; ++jn) {
        int br = jn * 16 + l15;
        int seg = ks * 4 + kq;
        bf16x8 b = *(const bf16x8*)&Bs[br * 64 + ((seg ^ (br & 7)) << 3)];
#pragma unroll
        for (int i = 0; i < 2; ++i) {
          acc[i][jn] = __builtin_amdgcn_mfma_f32_16x16x32_bf16(ah[i][ks], b, acc[i][jn], 0, 0, 0);
          acc[i][jn] = __builtin_amdgcn_mfma_f32_16x16x32_bf16(al[i][ks], b, acc[i][jn], 0, 0, 0);
        }
      }
    __syncthreads();
    // stage B lo
#pragma unroll
    for (int l = 0; l < 2; ++l) {
      int idx = tid + l * 256;
      int row = idx >> 3, seg = idx & 7;
      *(bf16x8*)&Bs[row * 64 + ((seg ^ (row & 7)) << 3)] =
          *(const bf16x8*)&Wt[(size_t)(n0 + row) * 2048 + 1024 + s * 64 + seg * 8];
    }
    __syncthreads();
#pragma unroll
    for (int ks = 0; ks < 2; ++ks)
#pragma unroll
      for (int jn = 0; jn < 4; ++jn) {
        int br = jn * 16 + l15;
        int seg = ks * 4 + kq;
        bf16x8 b = *(const bf16x8*)&Bs[br * 64 + ((seg ^ (br & 7)) << 3)];
#pragma unroll
        for (int i = 0; i < 2; ++i)
          acc[i][jn] = __builtin_amdgcn_mfma_f32_16x16x32_bf16(ah[i][ks], b, acc[i][jn], 0, 0, 0);
      }
  }
  // epilogue: bias, split to hi/lo, head-blocked store
#pragma unroll
  for (int i = 0; i < 2; ++i)
#pragma unroll
    for (int jn = 0; jn < 4; ++jn) {
      int n = n0 + jn * 16 + l15;
      int h = n >> 6, d = n & 63;
#pragma unroll
      for (int r = 0; r < 4; ++r) {
        int m = m0 + wave * 32 + i * 16 + kq * 4 + r;   // C/D row = (lane>>4)*4+reg
        float val = acc[i][jn][r] + bval[jn];
        short hb = f2bf(val);
        short lb = f2bf(val - bf2f(hb));
        Out[(size_t)m * 2048 + h * 128 + d] = hb;
        Out[(size_t)m * 2048 + h * 128 + 64 + d] = lb;
      }
    }
}

// ---------------- K2: split-bf16 MFMA Gram + circular-diagonal reduce ----------
// grid (16 u, 16 t, 16 h) per batch; tile 128x128, 4 waves as 2x2 of 64x64.
__global__ __launch_bounds__(256) void corr2_k(
    const short* __restrict__ Qs, const short* __restrict__ Ks,
    float* __restrict__ mcb)
{
  const int h = blockIdx.z;
  const int u0 = blockIdx.x * 128, t0 = blockIdx.y * 128;
  __shared__ __align__(16) short Qh[128 * 64];
  __shared__ __align__(16) short Ql[128 * 64];
  __shared__ __align__(16) short Kh[128 * 64];
  __shared__ __align__(16) short Kl[128 * 64];
  __shared__ float bins[256];
  const int tid = threadIdx.x;
  const int wave = tid >> 6, lane = tid & 63, l15 = lane & 15, kq = lane >> 4;
  const int wr = wave >> 1, wc = wave & 1;
  bins[tid] = 0.f;
#pragma unroll
  for (int l = 0; l < 4; ++l) {
    int idx = tid + l * 256;
    int row = idx >> 3, seg = idx & 7;
    size_t qsrc = (size_t)(t0 + row) * 2048 + h * 128 + seg * 8;
    size_t ksrc = (size_t)(u0 + row) * 2048 + h * 128 + seg * 8;
    int dst = row * 64 + ((seg ^ (row & 7)) << 3);
    *(bf16x8*)&Qh[dst] = *(const bf16x8*)&Qs[qsrc];
    *(bf16x8*)&Ql[dst] = *(const bf16x8*)&Qs[qsrc + 64];
    *(bf16x8*)&Kh[dst] = *(const bf16x8*)&Ks[ksrc];
    *(bf16x8*)&Kl[dst] = *(const bf16x8*)&Ks[ksrc + 64];
  }
  __syncthreads();
  f32x4 acc[4][4];
#pragma unroll
  for (int i = 0; i < 4; ++i)
#pragma unroll
    for (int j = 0; j < 4; ++j)
#pragma unroll
      for (int r = 0; r < 4; ++r) acc[i][j][r] = 0.f;

#pragma unroll
  for (int ksub = 0; ksub < 2; ++ksub) {
    int seg = ksub * 4 + kq;
    bf16x8 ah[4], al[4], bh[4], bl[4];
#pragma unroll
    for (int i = 0; i < 4; ++i) {
      int ar = wr * 64 + i * 16 + l15;
      int addr = ar * 64 + ((seg ^ (ar & 7)) << 3);
      ah[i] = *(const bf16x8*)&Qh[addr];
      al[i] = *(const bf16x8*)&Ql[addr];
    }
#pragma unroll
    for (int j = 0; j < 4; ++j) {
      int br = wc * 64 + j * 16 + l15;
      int addr = br * 64 + ((seg ^ (br & 7)) << 3);
      bh[j] = *(const bf16x8*)&Kh[addr];
      bl[j] = *(const bf16x8*)&Kl[addr];
    }
#pragma unroll
    for (int i = 0; i < 4; ++i)
#pragma unroll
      for (int j = 0; j < 4; ++j) {
        acc[i][j] = __builtin_amdgcn_mfma_f32_16x16x32_bf16(ah[i], bh[j], acc[i][j], 0, 0, 0);
        acc[i][j] = __builtin_amdgcn_mfma_f32_16x16x32_bf16(al[i], bh[j], acc[i][j], 0, 0, 0);
        acc[i][j] = __builtin_amdgcn_mfma_f32_16x16x32_bf16(ah[i], bl[j], acc[i][j], 0, 0, 0);
      }
  }
  // diagonal reduce: t = t0+wr*64+i*16+kq*4+r ; u = u0+wc*64+j*16+l15
  float dsum[7][4];
#pragma unroll
  for (int d = 0; d < 7; ++d)
#pragma unroll
    for (int r = 0; r < 4; ++r) dsum[d][r] = 0.f;
#pragma unroll
  for (int i = 0; i < 4; ++i)
#pragma unroll
    for (int j = 0; j < 4; ++j)
#pragma unroll
      for (int r = 0; r < 4; ++r) dsum[i - j + 3][r] += acc[i][j][r];
  const int base = (wr - wc) * 64 + kq * 4 - l15 + 127;
#pragma unroll
  for (int d = 0; d < 7; ++d)
#pragma unroll
    for (int r = 0; r < 4; ++r)
      atomicAdd(&bins[base + 16 * (d - 3) + r], dsum[d][r]);
  __syncthreads();
  if (tid < 255) {
    int tau = (t0 - u0 + tid - 127) & (SS - 1);
    atomicAdd(&mcb[h * SS + tau], bins[tid]);
  }
}

// ---------------- K3: radix-select top-409 + softmax per (b,h) -----------------
__global__ __launch_bounds__(256) void topk_k(
    const float* __restrict__ mc, int* __restrict__ sidx, float* __restrict__ sw)
{
  const int bh = blockIdx.x;
  __shared__ float vals[SS];
  __shared__ unsigned int keys[SS];
  __shared__ int el_i[KTOP];
  __shared__ float el_w[KTOP];
  __shared__ int icnt, cnt2;
  __shared__ unsigned int kmax_sh;
  __shared__ float Zsh;
  const int tid = threadIdx.x;
  const float scale = 1.0f / 512.0f;   // 1/(dh * sqrt(dh))

  for (int l = 0; l < 8; ++l) {
    int i = tid + l * 256;
    float v = mc[bh * SS + i] * scale;
    vals[i] = v;
    unsigned int u = __float_as_uint(v);
    keys[i] = (u & 0x80000000u) ? ~u : (u | 0x80000000u);
  }
  if (tid == 0) { kmax_sh = 0u; cnt2 = 0; Zsh = 0.f; }
  __syncthreads();

  unsigned int lm = 0u;
  for (int l = 0; l < 8; ++l) lm = max(lm, keys[tid + l * 256]);
  atomicMax(&kmax_sh, lm);

  unsigned int prefix = 0u;
  for (int bit = 31; bit >= 0; --bit) {
    unsigned int cand = prefix | (1u << bit);
    int c = 0;
    for (int l = 0; l < 8; ++l) c += (keys[tid + l * 256] >= cand) ? 1 : 0;
    __syncthreads();
    if (tid == 0) icnt = 0;
    __syncthreads();
    atomicAdd(&icnt, c);
    __syncthreads();
    if (icnt >= KTOP) prefix = cand;   // uniform across block
  }
  const unsigned int T = prefix;       // exact 409th-largest key
  __syncthreads();
  unsigned int km = kmax_sh;
  float vmax = __uint_as_float((km & 0x80000000u) ? (km ^ 0x80000000u) : ~km);

  for (int l = 0; l < 8; ++l) {
    int i = tid + l * 256;
    if (keys[i] > T) {
      int pos = atomicAdd(&cnt2, 1);
      el_i[pos] = i;
      el_w[pos] = expf(vals[i] - vmax);
    }
  }
  __syncthreads();
  if (tid == 0) {   // fill remaining slots with ==T, lowest index first
    int pos = cnt2;
    for (int i = 0; i < SS && pos < KTOP; ++i)
      if (keys[i] == T) { el_i[pos] = i; el_w[pos] = expf(vals[i] - vmax); ++pos; }
  }
  __syncthreads();
  float z = 0.f;
  for (int l = tid; l < KTOP; l += 256) z += el_w[l];
  atomicAdd(&Zsh, z);
  __syncthreads();
  float invZ = 1.0f / Zsh;
  for (int l = tid; l < KTOP; l += 256) {
    sidx[bh * KTOP + l] = el_i[l];
    sw[bh * KTOP + l]   = el_w[l] * invZ;
  }
}

// ---------------- K4: xbar[b,h,:] = sum_sel w * xv[b,idx,:] --------------------
__global__ __launch_bounds__(256) void xbar_k(
    const int* __restrict__ sidx, const float* __restrict__ sw,
    const float* __restrict__ xv, float* __restrict__ xbar)
{
  const int bh = blockIdx.x, b = bh >> 4;
  __shared__ int il[KTOP];
  __shared__ float wl[KTOP];
  const int tid = threadIdx.x;
  for (int l = tid; l < KTOP; l += 256) { il[l] = sidx[bh * KTOP + l]; wl[l] = sw[bh * KTOP + l]; }
  __syncthreads();
  const float4* xv4 = (const float4*)xv;
  float4 acc = make_float4(0.f, 0.f, 0.f, 0.f);
  for (int r = 0; r < KTOP; ++r) {
    float w = wl[r];
    float4 v = xv4[(size_t)(b * SS + il[r]) * 256 + tid];
    acc.x += w * v.x; acc.y += w * v.y; acc.z += w * v.z; acc.w += w * v.w;
  }
  ((float4*)xbar)[(size_t)bh * 256 + tid] = acc;
}

// ---------------- K5a: init attended=bv, outrow=bo -----------------------------
__global__ __launch_bounds__(256) void initbias_k(
    const float* __restrict__ bv, const float* __restrict__ bo,
    float* __restrict__ att, float* __restrict__ orow)
{
  int i = blockIdx.x * 256 + threadIdx.x;   // < 8192
  if (i < 4096) att[i] = bv[i & 1023];
  else          orow[i - 4096] = bo[i & 1023];
}

// ---------------- K5: attended[b,j] += sum_i xbar[b,j/64,i]*wv[i,j] ------------
__global__ __launch_bounds__(256) void attend_k(
    const float* __restrict__ xbar, const float* __restrict__ wv,
    float* __restrict__ att)
{
  const int b = blockIdx.y, i0 = blockIdx.x * 64;
  __shared__ float xs[16 * 64];
  const int tid = threadIdx.x;
#pragma unroll
  for (int l = 0; l < 4; ++l) {
    int f = tid + l * 256;
    xs[f] = xbar[(size_t)(b * 16 + (f >> 6)) * 1024 + i0 + (f & 63)];
  }
  __syncthreads();
  const float4* wv4 = (const float4*)wv;
  const int h = tid >> 4;
  float4 acc = make_float4(0.f, 0.f, 0.f, 0.f);
  for (int m = 0; m < 64; ++m) {
    float xvs = xs[h * 64 + m];
    float4 w = wv4[(size_t)(i0 + m) * 256 + tid];
    acc.x += xvs * w.x; acc.y += xvs * w.y; acc.z += xvs * w.z; acc.w += xvs * w.w;
  }
  float* dst = att + (size_t)b * 1024 + tid * 4;
  atomicAdd(dst + 0, acc.x); atomicAdd(dst + 1, acc.y);
  atomicAdd(dst + 2, acc.z); atomicAdd(dst + 3, acc.w);
}

// ---------------- K6: outrow[b,n] += sum_m att[b,m]*wo[m,n] --------------------
__global__ __launch_bounds__(256) void oproj_k(
    const float* __restrict__ att, const float* __restrict__ wo,
    float* __restrict__ orow)
{
  const int b = blockIdx.y, m0 = blockIdx.x * 64;
  __shared__ float as_[64];
  const int tid = threadIdx.x;
  if (tid < 64) as_[tid] = att[(size_t)b * 1024 + m0 + tid];
  __syncthreads();
  const float4* wo4 = (const float4*)wo;
  float4 acc = make_float4(0.f, 0.f, 0.f, 0.f);
  for (int m = 0; m < 64; ++m) {
    float a = as_[m];
    float4 w = wo4[(size_t)(m0 + m) * 256 + tid];
    acc.x += a * w.x; acc.y += a * w.y; acc.z += a * w.z; acc.w += a * w.w;
  }
  float* dst = orow + (size_t)b * 1024 + tid * 4;
  atomicAdd(dst + 0, acc.x); atomicAdd(dst + 1, acc.y);
  atomicAdd(dst + 2, acc.z); atomicAdd(dst + 3, acc.w);
}

// ---------------- K7: broadcast outrow across S --------------------------------
__global__ __launch_bounds__(256) void bcast_k(
    const float* __restrict__ orow, float* __restrict__ out)
{
  int idx = blockIdx.x * 256 + threadIdx.x;           // float4 index
  const float4* o4 = (const float4*)orow;
  ((float4*)out)[idx] = o4[((idx >> 19) << 8) | (idx & 255)];
}

extern "C" void kernel_launch(void* const* d_in, const int* in_sizes, int n_in,
                              void* d_out, int out_size, void* d_ws, size_t ws_size,
                              hipStream_t stream) {
  (void)in_sizes; (void)n_in; (void)out_size; (void)ws_size;
  const float* xq = (const float*)d_in[0];
  const float* xk = (const float*)d_in[1];
  const float* xv = (const float*)d_in[2];
  const float* wq = (const float*)d_in[3];
  const float* bq = (const float*)d_in[4];
  const float* wk = (const float*)d_in[5];
  const float* bk = (const float*)d_in[6];
  const float* wv = (const float*)d_in[7];
  const float* bv = (const float*)d_in[8];
  const float* wo = (const float*)d_in[9];
  const float* bo = (const float*)d_in[10];
  float* out = (float*)d_out;

  // ---- scratch in d_out (32 MB, overwritten by bcast_k at the end) ----
  char* ob = (char*)d_out;
  short* Wqt = (short*)(ob);                  // 4 MB
  short* Wkt = (short*)(ob + ( 4u << 20));    // 4 MB
  short* Xqs = (short*)(ob + ( 8u << 20));    // 8 MB (per batch)
  short* Xks = (short*)(ob + (16u << 20));    // 8 MB (per batch)

  // ---- d_ws layout: exactly round-1-proven 17,805,824 bytes ----
  char* base = (char*)d_ws;
  short* Qsb = (short*)(base);                // 8 MB (2048 x 2048 shorts)
  short* Ksb = (short*)(base + (8u << 20));   // 8 MB
  size_t off = (16u << 20);
  float* mc   = (float*)(base + off); off += (size_t)SB * SH * SS * 4;   // 512 KB
  int*   sidx = (int*)  (base + off); off += (size_t)SB * SH * KTOP * 4;
  float* sw   = (float*)(base + off); off += (size_t)SB * SH * KTOP * 4;
  float* xbar = (float*)(base + off); off += (size_t)SB * SH * SD * 4;   // 256 KB
  float* att  = (float*)(base + off); off += (size_t)SB * SD * 4;
  float* orow = (float*)(base + off);

  splitwt_k<<<dim3(16, 16, 2), 256, 0, stream>>>(wq, wk, Wqt, Wkt);
  hipMemsetAsync(mc, 0, (size_t)SB * SH * SS * sizeof(float), stream);

  for (int b = 0; b < SB; ++b) {
    xsplit_k<<<dim3(2048, 1, 2), 256, 0, stream>>>(
        xq + (size_t)b * SS * SD, xk + (size_t)b * SS * SD, Xqs, Xks);
    proj_k<<<dim3(16, 16, 2), 256, 0, stream>>>(
        Xqs, Wqt, bq, Qsb, Xks, Wkt, bk, Ksb);
    corr2_k<<<dim3(16, 16, 16), 256, 0, stream>>>(Qsb, Ksb, mc + (size_t)b * SH * SS);
  }
  topk_k<<<dim3(SB * SH), 256, 0, stream>>>(mc, sidx, sw);
  xbar_k<<<dim3(SB * SH), 256, 0, stream>>>(sidx, sw, xv, xbar);
  initbias_k<<<dim3(32), 256, 0, stream>>>(bv, bo, att, orow);
  attend_k<<<dim3(16, SB), 256, 0, stream>>>(xbar, wv, att);
  oproj_k<<<dim3(16, SB), 256, 0, stream>>>(att, wo, orow);
  bcast_k<<<dim3(8192), 256, 0, stream>>>(orow, out);
}

// Round 4
// 717.681 us; speedup vs baseline: 2.7905x; 1.7955x over previous
//
#include <hip/hip_runtime.h>
#include <math.h>

#define SB 4
#define SS 2048
#define SD 1024
#define SH 16
#define KTOP 409   // max(2048//5, 1)

typedef float f32x4  __attribute__((ext_vector_type(4)));
typedef short bf16x8 __attribute__((ext_vector_type(8)));
typedef short s16x4  __attribute__((ext_vector_type(4)));

__device__ __forceinline__ short f2bf(float x) {
  unsigned u = __float_as_uint(x);
  u += 0x7fff + ((u >> 16) & 1);           // RNE
  return (short)(u >> 16);
}
__device__ __forceinline__ float bf2f(short s) {
  return __uint_as_float(((unsigned)(unsigned short)s) << 16);
}

// ---------------- P0: transpose + split W[k][n] -> Wt[n][{hi:0..1023|lo:1024..2047}]
__global__ __launch_bounds__(256) void splitwt_k(
    const float* __restrict__ wq, const float* __restrict__ wk,
    short* __restrict__ wqt, short* __restrict__ wkt)
{
  const float* W = blockIdx.z ? wk : wq;
  short* Wt = blockIdx.z ? wkt : wqt;
  const int n0 = blockIdx.x * 64, k0 = blockIdx.y * 64;
  __shared__ float T[64][65];
  const int tid = threadIdx.x;
#pragma unroll
  for (int l = 0; l < 4; ++l) {
    int idx = tid + l * 256;
    int r = idx >> 4, c4 = (idx & 15) << 2;
    float4 v = *(const float4*)&W[(size_t)(k0 + r) * SD + n0 + c4];
    T[r][c4 + 0] = v.x; T[r][c4 + 1] = v.y; T[r][c4 + 2] = v.z; T[r][c4 + 3] = v.w;
  }
  __syncthreads();
#pragma unroll
  for (int l = 0; l < 4; ++l) {
    int idx = tid + l * 256;
    int nr = idx >> 4, k4 = (idx & 15) << 2;
    s16x4 hi, lo;
#pragma unroll
    for (int j = 0; j < 4; ++j) {
      float x = T[k4 + j][nr];
      short hb = f2bf(x);
      hi[j] = hb; lo[j] = f2bf(x - bf2f(hb));
    }
    *(s16x4*)&Wt[(size_t)(n0 + nr) * 2048 + k0 + k4] = hi;
    *(s16x4*)&Wt[(size_t)(n0 + nr) * 2048 + 1024 + k0 + k4] = lo;
  }
}

// ---------------- K1: split-bf16 MFMA projection (16x16x32), fp32 transposed out
// C[t][n] = X[t][:] @ W[:,n] + bias[n]; written as Qt[n][t] (fp32) for FFT columns.
// grid (16 n-tiles, 16 m-tiles, 2 {q,k}), block 256. MFMA core identical to r3.
__global__ __launch_bounds__(256) void proj_k(
    const float* __restrict__ xq, const short* __restrict__ Wq,
    const float* __restrict__ bq, float* __restrict__ Qt,
    const float* __restrict__ xk, const short* __restrict__ Wk,
    const float* __restrict__ bk, float* __restrict__ Kt)
{
  const float* X; const short* Wt; const float* bias; float* Out;
  if (blockIdx.z == 0) { X = xq; Wt = Wq; bias = bq; Out = Qt; }
  else                 { X = xk; Wt = Wk; bias = bk; Out = Kt; }
  const int n0 = blockIdx.x * 64, m0 = blockIdx.y * 128;
  __shared__ __align__(16) short Ah[128 * 64];
  __shared__ __align__(16) short Al[128 * 64];
  __shared__ __align__(16) short Bs[64 * 64];
  const int tid = threadIdx.x;
  const int wave = tid >> 6, lane = tid & 63, l15 = lane & 15, kq = lane >> 4;
  f32x4 acc[2][4];
#pragma unroll
  for (int i = 0; i < 2; ++i)
#pragma unroll
    for (int j = 0; j < 4; ++j)
#pragma unroll
      for (int r = 0; r < 4; ++r) acc[i][j][r] = 0.f;
  float bval[4];
#pragma unroll
  for (int jn = 0; jn < 4; ++jn) bval[jn] = bias[n0 + jn * 16 + l15];

  for (int s = 0; s < 16; ++s) {
    __syncthreads();
    // stage A: read X fp32, split to hi/lo bf16 (same math as validated xsplit)
#pragma unroll
    for (int l = 0; l < 4; ++l) {
      int idx = tid + l * 256;
      int row = idx >> 3, seg = idx & 7;
      const float* src = &X[(size_t)(m0 + row) * SD + s * 64 + seg * 8];
      float4 va = *(const float4*)src;
      float4 vb = *(const float4*)(src + 4);
      float xs[8] = {va.x, va.y, va.z, va.w, vb.x, vb.y, vb.z, vb.w};
      bf16x8 hi, lo;
#pragma unroll
      for (int j = 0; j < 8; ++j) {
        short hb = f2bf(xs[j]);
        hi[j] = hb; lo[j] = f2bf(xs[j] - bf2f(hb));
      }
      int dst = row * 64 + ((seg ^ (row & 7)) << 3);
      *(bf16x8*)&Ah[dst] = hi;
      *(bf16x8*)&Al[dst] = lo;
    }
    // stage B hi
#pragma unroll
    for (int l = 0; l < 2; ++l) {
      int idx = tid + l * 256;
      int row = idx >> 3, seg = idx & 7;
      *(bf16x8*)&Bs[row * 64 + ((seg ^ (row & 7)) << 3)] =
          *(const bf16x8*)&Wt[(size_t)(n0 + row) * 2048 + s * 64 + seg * 8];
    }
    __syncthreads();
    bf16x8 ah[2][2], al[2][2];
#pragma unroll
    for (int i = 0; i < 2; ++i)
#pragma unroll
      for (int ks = 0; ks < 2; ++ks) {
        int ar = wave * 32 + i * 16 + l15;
        int seg = ks * 4 + kq;
        int addr = ar * 64 + ((seg ^ (ar & 7)) << 3);
        ah[i][ks] = *(const bf16x8*)&Ah[addr];
        al[i][ks] = *(const bf16x8*)&Al[addr];
      }
#pragma unroll
    for (int ks = 0; ks < 2; ++ks)
#pragma unroll
      for (int jn = 0; jn < 4; ++jn) {
        int br = jn * 16 + l15;
        int seg = ks * 4 + kq;
        bf16x8 b = *(const bf16x8*)&Bs[br * 64 + ((seg ^ (br & 7)) << 3)];
#pragma unroll
        for (int i = 0; i < 2; ++i) {
          acc[i][jn] = __builtin_amdgcn_mfma_f32_16x16x32_bf16(ah[i][ks], b, acc[i][jn], 0, 0, 0);
          acc[i][jn] = __builtin_amdgcn_mfma_f32_16x16x32_bf16(al[i][ks], b, acc[i][jn], 0, 0, 0);
        }
      }
    __syncthreads();
    // stage B lo
#pragma unroll
    for (int l = 0; l < 2; ++l) {
      int idx = tid + l * 256;
      int row = idx >> 3, seg = idx & 7;
      *(bf16x8*)&Bs[row * 64 + ((seg ^ (row & 7)) << 3)] =
          *(const bf16x8*)&Wt[(size_t)(n0 + row) * 2048 + 1024 + s * 64 + seg * 8];
    }
    __syncthreads();
#pragma unroll
    for (int ks = 0; ks < 2; ++ks)
#pragma unroll
      for (int jn = 0; jn < 4; ++jn) {
        int br = jn * 16 + l15;
        int seg = ks * 4 + kq;
        bf16x8 b = *(const bf16x8*)&Bs[br * 64 + ((seg ^ (br & 7)) << 3)];
#pragma unroll
        for (int i = 0; i < 2; ++i)
          acc[i][jn] = __builtin_amdgcn_mfma_f32_16x16x32_bf16(ah[i][ks], b, acc[i][jn], 0, 0, 0);
      }
  }
  // epilogue: bias, fp32 store transposed [n][t] (4 consecutive t per reg quad)
#pragma unroll
  for (int i = 0; i < 2; ++i)
#pragma unroll
    for (int jn = 0; jn < 4; ++jn) {
      int n = n0 + jn * 16 + l15;
      int tb = m0 + wave * 32 + i * 16 + kq * 4;   // C/D row = (lane>>4)*4+reg
      float4 v = make_float4(acc[i][jn][0] + bval[jn], acc[i][jn][1] + bval[jn],
                             acc[i][jn][2] + bval[jn], acc[i][jn][3] + bval[jn]);
      *(float4*)&Out[(size_t)n * SS + tb] = v;
    }
}

// ---------------- K2: packed FFT (re=q, im=k) + cross-spectrum accumulate ------
// grid (16 dgroups, 16 heads) per batch. P[b][h][f] += sum_d Qf conj(Kf).
__global__ __launch_bounds__(256) void fftcorr_k(
    const float* __restrict__ Qt, const float* __restrict__ Kt,
    float* __restrict__ Pb)
{
  const int dg = blockIdx.x, h = blockIdx.y;
  __shared__ float re[2048], im[2048];
  __shared__ float twc[1024], tws[1024];
  __shared__ float pr[2048], pi[2048];
  const int tid = threadIdx.x;
  // forward twiddles: w_j = exp(-2*pi*i*j/2048)
  for (int j = tid; j < 1024; j += 256) {
    float a = 6.2831853071795864769f * (float)j / 2048.0f;
    twc[j] = cosf(a); tws[j] = -sinf(a);
  }
#pragma unroll
  for (int l = 0; l < 8; ++l) { int f = tid + l * 256; pr[f] = 0.f; pi[f] = 0.f; }
  __syncthreads();

  for (int dd = 0; dd < 4; ++dd) {
    const int n = h * 64 + dg * 4 + dd;
    // bit-reversed load: re = q column, im = k column
#pragma unroll
    for (int l = 0; l < 8; ++l) {
      int t = tid + l * 256;
      int rv = __brev((unsigned)t) >> 21;
      re[rv] = Qt[(size_t)n * SS + t];
      im[rv] = Kt[(size_t)n * SS + t];
    }
    __syncthreads();
    // 11 DIT stages
    for (int s = 1; s <= 11; ++s) {
      const int half = 1 << (s - 1);
      const int m = half << 1;
      const int tshift = 11 - s;
#pragma unroll
      for (int l = 0; l < 4; ++l) {
        int bfly = tid + l * 256;
        int g = bfly >> (s - 1), p = bfly & (half - 1);
        int i0 = g * m + p, i1 = i0 + half;
        int tj = p << tshift;
        float wr_ = twc[tj], wi_ = tws[tj];
        float xr = re[i1], xi = im[i1];
        float tr = wr_ * xr - wi_ * xi;
        float ti = wr_ * xi + wi_ * xr;
        float ur = re[i0], ui = im[i0];
        re[i1] = ur - tr; im[i1] = ui - ti;
        re[i0] = ur + tr; im[i0] = ui + ti;
      }
      __syncthreads();
    }
    // unpack two real spectra and accumulate P += Qf * conj(Kf)
#pragma unroll
    for (int l = 0; l < 8; ++l) {
      int f = tid + l * 256;
      int fc = (2048 - f) & 2047;
      float Zr = re[f], Zi = im[f];
      float Zcr = re[fc], Zci = -im[fc];
      float Qr = 0.5f * (Zr + Zcr), Qi = 0.5f * (Zi + Zci);
      float Kr = 0.5f * (Zi - Zci), Ki = -0.5f * (Zr - Zcr);
      pr[f] += Qr * Kr + Qi * Ki;
      pi[f] += Qi * Kr - Qr * Ki;
    }
    __syncthreads();
  }
#pragma unroll
  for (int l = 0; l < 8; ++l) {
    int f = tid + l * 256;
    atomicAdd(&Pb[((size_t)h * SS + f) * 2 + 0], pr[f]);
    atomicAdd(&Pb[((size_t)h * SS + f) * 2 + 1], pi[f]);
  }
}

// ---------------- K3: inverse FFT + byte-radix top-409 + softmax, per (b,h) ----
__global__ __launch_bounds__(256) void ifft_topk_k(
    const float* __restrict__ P, int* __restrict__ sidx, float* __restrict__ sw)
{
  const int bh = blockIdx.x;
  __shared__ float re[2048], im[2048];
  __shared__ float twc[1024], tws[1024];
  __shared__ unsigned keys[2048];
  __shared__ int el_i[KTOP];
  __shared__ float el_w[KTOP];
  __shared__ int hist[256];
  __shared__ int scan_sh[256];
  __shared__ int cnt2, tiecnt, sel_v;
  __shared__ unsigned kmax_sh;
  __shared__ float Zsh;
  const int tid = threadIdx.x;
  const float SCL = 1.0f / (2048.0f * 512.0f);   // 1/N * 1/(dh*sqrt(dh))

  // inverse twiddles: w_j = exp(+2*pi*i*j/2048)
  for (int j = tid; j < 1024; j += 256) {
    float a = 6.2831853071795864769f * (float)j / 2048.0f;
    twc[j] = cosf(a); tws[j] = sinf(a);
  }
  if (tid == 0) { cnt2 = 0; tiecnt = 0; kmax_sh = 0u; Zsh = 0.f; }
  // bit-reversed load of P[bh][f]
#pragma unroll
  for (int l = 0; l < 8; ++l) {
    int f = tid + l * 256;
    int rv = __brev((unsigned)f) >> 21;
    re[rv] = P[((size_t)bh * SS + f) * 2 + 0];
    im[rv] = P[((size_t)bh * SS + f) * 2 + 1];
  }
  __syncthreads();
  for (int s = 1; s <= 11; ++s) {
    const int half = 1 << (s - 1);
    const int m = half << 1;
    const int tshift = 11 - s;
#pragma unroll
    for (int l = 0; l < 4; ++l) {
      int bfly = tid + l * 256;
      int g = bfly >> (s - 1), p = bfly & (half - 1);
      int i0 = g * m + p, i1 = i0 + half;
      int tj = p << tshift;
      float wr_ = twc[tj], wi_ = tws[tj];
      float xr = re[i1], xi = im[i1];
      float tr = wr_ * xr - wi_ * xi;
      float ti = wr_ * xi + wi_ * xr;
      float ur = re[i0], ui = im[i0];
      re[i1] = ur - tr; im[i1] = ui - ti;
      re[i0] = ur + tr; im[i0] = ui + ti;
    }
    __syncthreads();
  }
  // vals = scaled real part; monotone keys
  unsigned lm = 0u;
#pragma unroll
  for (int l = 0; l < 8; ++l) {
    int i = tid + l * 256;
    float v = re[i] * SCL;
    re[i] = v;
    unsigned u = __float_as_uint(v);
    unsigned k = (u & 0x80000000u) ? ~u : (u | 0x80000000u);
    keys[i] = k;
    lm = max(lm, k);
  }
  atomicMax(&kmax_sh, lm);
  __syncthreads();

  // 4-pass byte radix: find T = key value of rank KTOP
  unsigned prefix = 0u;
  int remaining = KTOP;
  for (int p = 3; p >= 0; --p) {
    hist[tid] = 0;
    __syncthreads();
    unsigned mask_hi = (p == 3) ? 0u : (0xFFFFFFFFu << ((p + 1) * 8));
#pragma unroll
    for (int l = 0; l < 8; ++l) {
      unsigned k = keys[tid + l * 256];
      if ((k & mask_hi) == prefix) atomicAdd(&hist[(k >> (p * 8)) & 255], 1);
    }
    __syncthreads();
    scan_sh[tid] = hist[tid];
    __syncthreads();
    for (int off = 1; off < 256; off <<= 1) {
      int add = (tid + off < 256) ? scan_sh[tid + off] : 0;
      __syncthreads();
      scan_sh[tid] += add;
      __syncthreads();
    }
    if (scan_sh[tid] >= remaining && (tid == 255 || scan_sh[tid + 1] < remaining))
      sel_v = tid;
    __syncthreads();
    int v = sel_v;
    int above = (v == 255) ? 0 : scan_sh[v + 1];
    remaining -= above;
    prefix |= ((unsigned)v) << (p * 8);
    __syncthreads();
  }
  const unsigned T = prefix;
  unsigned km = kmax_sh;
  float vmax = __uint_as_float((km & 0x80000000u) ? (km ^ 0x80000000u) : ~km);

  // compact strictly-greater; count ties
#pragma unroll
  for (int l = 0; l < 8; ++l) {
    int i = tid + l * 256;
    unsigned k = keys[i];
    if (k > T) {
      int pos = atomicAdd(&cnt2, 1);
      el_i[pos] = i;
      el_w[pos] = expf(re[i] - vmax);
    } else if (k == T) {
      atomicAdd(&tiecnt, 1);
    }
  }
  __syncthreads();
  int need = KTOP - cnt2;
  if (tiecnt == need) {          // common case: ties exactly fill, order irrelevant
#pragma unroll
    for (int l = 0; l < 8; ++l) {
      int i = tid + l * 256;
      if (keys[i] == T) {
        int pos = atomicAdd(&cnt2, 1);
        el_i[pos] = i;
        el_w[pos] = expf(re[i] - vmax);
      }
    }
  } else if (tid == 0) {         // rare: lowest-index ties first (jax rule)
    int pos = cnt2;
    for (int i = 0; i < SS && pos < KTOP; ++i)
      if (keys[i] == T) { el_i[pos] = i; el_w[pos] = expf(re[i] - vmax); ++pos; }
  }
  __syncthreads();
  float z = 0.f;
  for (int l = tid; l < KTOP; l += 256) z += el_w[l];
  atomicAdd(&Zsh, z);
  __syncthreads();
  float invZ = 1.0f / Zsh;
  for (int l = tid; l < KTOP; l += 256) {
    sidx[bh * KTOP + l] = el_i[l];
    sw[bh * KTOP + l]   = el_w[l] * invZ;
  }
}

// ---------------- K4: xbar[b,h,:] = sum_sel w * xv[b,idx,:] --------------------
__global__ __launch_bounds__(256) void xbar_k(
    const int* __restrict__ sidx, const float* __restrict__ sw,
    const float* __restrict__ xv, float* __restrict__ xbar)
{
  const int bh = blockIdx.x, b = bh >> 4;
  __shared__ int il[KTOP];
  __shared__ float wl[KTOP];
  const int tid = threadIdx.x;
  for (int l = tid; l < KTOP; l += 256) { il[l] = sidx[bh * KTOP + l]; wl[l] = sw[bh * KTOP + l]; }
  __syncthreads();
  const float4* xv4 = (const float4*)xv;
  float4 acc = make_float4(0.f, 0.f, 0.f, 0.f);
  for (int r = 0; r < KTOP; ++r) {
    float w = wl[r];
    float4 v = xv4[(size_t)(b * SS + il[r]) * 256 + tid];
    acc.x += w * v.x; acc.y += w * v.y; acc.z += w * v.z; acc.w += w * v.w;
  }
  ((float4*)xbar)[(size_t)bh * 256 + tid] = acc;
}

// ---------------- K5a: init attended=bv, outrow=bo -----------------------------
__global__ __launch_bounds__(256) void initbias_k(
    const float* __restrict__ bv, const float* __restrict__ bo,
    float* __restrict__ att, float* __restrict__ orow)
{
  int i = blockIdx.x * 256 + threadIdx.x;   // < 8192
  if (i < 4096) att[i] = bv[i & 1023];
  else          orow[i - 4096] = bo[i & 1023];
}

// ---------------- K5: attended[b,j] += sum_i xbar[b,j/64,i]*wv[i,j] ------------
__global__ __launch_bounds__(256) void attend_k(
    const float* __restrict__ xbar, const float* __restrict__ wv,
    float* __restrict__ att)
{
  const int b = blockIdx.y, i0 = blockIdx.x * 64;
  __shared__ float xs[16 * 64];
  const int tid = threadIdx.x;
#pragma unroll
  for (int l = 0; l < 4; ++l) {
    int f = tid + l * 256;
    xs[f] = xbar[(size_t)(b * 16 + (f >> 6)) * 1024 + i0 + (f & 63)];
  }
  __syncthreads();
  const float4* wv4 = (const float4*)wv;
  const int h = tid >> 4;
  float4 acc = make_float4(0.f, 0.f, 0.f, 0.f);
  for (int m = 0; m < 64; ++m) {
    float xvs = xs[h * 64 + m];
    float4 w = wv4[(size_t)(i0 + m) * 256 + tid];
    acc.x += xvs * w.x; acc.y += xvs * w.y; acc.z += xvs * w.z; acc.w += xvs * w.w;
  }
  float* dst = att + (size_t)b * 1024 + tid * 4;
  atomicAdd(dst + 0, acc.x); atomicAdd(dst + 1, acc.y);
  atomicAdd(dst + 2, acc.z); atomicAdd(dst + 3, acc.w);
}

// ---------------- K6: outrow[b,n] += sum_m att[b,m]*wo[m,n] --------------------
__global__ __launch_bounds__(256) void oproj_k(
    const float* __restrict__ att, const float* __restrict__ wo,
    float* __restrict__ orow)
{
  const int b = blockIdx.y, m0 = blockIdx.x * 64;
  __shared__ float as_[64];
  const int tid = threadIdx.x;
  if (tid < 64) as_[tid] = att[(size_t)b * 1024 + m0 + tid];
  __syncthreads();
  const float4* wo4 = (const float4*)wo;
  float4 acc = make_float4(0.f, 0.f, 0.f, 0.f);
  for (int m = 0; m < 64; ++m) {
    float a = as_[m];
    float4 w = wo4[(size_t)(m0 + m) * 256 + tid];
    acc.x += a * w.x; acc.y += a * w.y; acc.z += a * w.z; acc.w += a * w.w;
  }
  float* dst = orow + (size_t)b * 1024 + tid * 4;
  atomicAdd(dst + 0, acc.x); atomicAdd(dst + 1, acc.y);
  atomicAdd(dst + 2, acc.z); atomicAdd(dst + 3, acc.w);
}

// ---------------- K7: broadcast outrow across S --------------------------------
__global__ __launch_bounds__(256) void bcast_k(
    const float* __restrict__ orow, float* __restrict__ out)
{
  int idx = blockIdx.x * 256 + threadIdx.x;           // float4 index
  const float4* o4 = (const float4*)orow;
  ((float4*)out)[idx] = o4[((idx >> 19) << 8) | (idx & 255)];
}

extern "C" void kernel_launch(void* const* d_in, const int* in_sizes, int n_in,
                              void* d_out, int out_size, void* d_ws, size_t ws_size,
                              hipStream_t stream) {
  (void)in_sizes; (void)n_in; (void)out_size; (void)ws_size;
  const float* xq = (const float*)d_in[0];
  const float* xk = (const float*)d_in[1];
  const float* xv = (const float*)d_in[2];
  const float* wq = (const float*)d_in[3];
  const float* bq = (const float*)d_in[4];
  const float* wk = (const float*)d_in[5];
  const float* bk = (const float*)d_in[6];
  const float* wv = (const float*)d_in[7];
  const float* bv = (const float*)d_in[8];
  const float* wo = (const float*)d_in[9];
  const float* bo = (const float*)d_in[10];
  float* out = (float*)d_out;

  // ---- scratch in d_out (32 MB; all dead before bcast_k overwrites it) ----
  char* ob = (char*)d_out;
  float* Qt  = (float*)(ob);                   // 8 MB  [n][t] fp32
  float* Kt  = (float*)(ob + ( 8u << 20));     // 8 MB
  short* Wqt = (short*)(ob + (16u << 20));     // 4 MB
  short* Wkt = (short*)(ob + (20u << 20));     // 4 MB (24..32 MB unused)

  // ---- d_ws: ~2 MB ----
  char* base = (char*)d_ws;
  float* P = (float*)base;                     // B*H*S complex = 1 MB
  size_t off = (size_t)SB * SH * SS * 2 * 4;
  int*   sidx = (int*)  (base + off); off += (size_t)SB * SH * KTOP * 4;
  float* sw   = (float*)(base + off); off += (size_t)SB * SH * KTOP * 4;
  float* xbar = (float*)(base + off); off += (size_t)SB * SH * SD * 4;
  float* att  = (float*)(base + off); off += (size_t)SB * SD * 4;
  float* orow = (float*)(base + off);

  splitwt_k<<<dim3(16, 16, 2), 256, 0, stream>>>(wq, wk, Wqt, Wkt);
  hipMemsetAsync(P, 0, (size_t)SB * SH * SS * 2 * sizeof(float), stream);

  for (int b = 0; b < SB; ++b) {
    proj_k<<<dim3(16, 16, 2), 256, 0, stream>>>(
        xq + (size_t)b * SS * SD, Wqt, bq, Qt,
        xk + (size_t)b * SS * SD, Wkt, bk, Kt);
    fftcorr_k<<<dim3(16, 16), 256, 0, stream>>>(
        Qt, Kt, P + (size_t)b * SH * SS * 2);
  }
  ifft_topk_k<<<dim3(SB * SH), 256, 0, stream>>>(P, sidx, sw);
  xbar_k<<<dim3(SB * SH), 256, 0, stream>>>(sidx, sw, xv, xbar);
  initbias_k<<<dim3(32), 256, 0, stream>>>(bv, bo, att, orow);
  attend_k<<<dim3(16, SB), 256, 0, stream>>>(xbar, wv, att);
  oproj_k<<<dim3(16, SB), 256, 0, stream>>>(att, wo, orow);
  bcast_k<<<dim3(8192), 256, 0, stream>>>(orow, out);
}

// Round 5
// 541.500 us; speedup vs baseline: 3.6984x; 1.3254x over previous
//
#include <hip/hip_runtime.h>
#include <math.h>

#define SB 4
#define SS 2048
#define SD 1024
#define SH 16
#define KTOP 409   // max(2048//5, 1)

typedef float f32x4  __attribute__((ext_vector_type(4)));
typedef short bf16x8 __attribute__((ext_vector_type(8)));
typedef short s16x4  __attribute__((ext_vector_type(4)));

__device__ __forceinline__ short f2bf(float x) {
  unsigned u = __float_as_uint(x);
  u += 0x7fff + ((u >> 16) & 1);           // RNE
  return (short)(u >> 16);
}
__device__ __forceinline__ float bf2f(short s) {
  return __uint_as_float(((unsigned)(unsigned short)s) << 16);
}

// ---------------- P-1: forward twiddle table w_j = exp(-2pi i j/2048) ----------
__global__ __launch_bounds__(256) void twiddle_k(float2* __restrict__ twtab) {
  int j = blockIdx.x * 256 + threadIdx.x;   // < 1024
  float a = 6.2831853071795864769f * (float)j / 2048.0f;
  twtab[j] = make_float2(cosf(a), -sinf(a));
}

// ---------------- P0: transpose + split W[k][n] -> Wt[n][{hi:0..1023|lo:1024..2047}]
__global__ __launch_bounds__(256) void splitwt_k(
    const float* __restrict__ wq, const float* __restrict__ wk,
    short* __restrict__ wqt, short* __restrict__ wkt)
{
  const float* W = blockIdx.z ? wk : wq;
  short* Wt = blockIdx.z ? wkt : wqt;
  const int n0 = blockIdx.x * 64, k0 = blockIdx.y * 64;
  __shared__ float T[64][65];
  const int tid = threadIdx.x;
#pragma unroll
  for (int l = 0; l < 4; ++l) {
    int idx = tid + l * 256;
    int r = idx >> 4, c4 = (idx & 15) << 2;
    float4 v = *(const float4*)&W[(size_t)(k0 + r) * SD + n0 + c4];
    T[r][c4 + 0] = v.x; T[r][c4 + 1] = v.y; T[r][c4 + 2] = v.z; T[r][c4 + 3] = v.w;
  }
  __syncthreads();
#pragma unroll
  for (int l = 0; l < 4; ++l) {
    int idx = tid + l * 256;
    int nr = idx >> 4, k4 = (idx & 15) << 2;
    s16x4 hi, lo;
#pragma unroll
    for (int j = 0; j < 4; ++j) {
      float x = T[k4 + j][nr];
      short hb = f2bf(x);
      hi[j] = hb; lo[j] = f2bf(x - bf2f(hb));
    }
    *(s16x4*)&Wt[(size_t)(n0 + nr) * 2048 + k0 + k4] = hi;
    *(s16x4*)&Wt[(size_t)(n0 + nr) * 2048 + 1024 + k0 + k4] = lo;
  }
}

// ---------------- K1: split-bf16 MFMA projection (16x16x32), 64x64 tile --------
// grid (16 n, 32 m, 2 {q,k}), block 256 = 4 waves in 2x2, 32x32 per wave.
// LDS 32 KB -> 4 blocks/CU. Out written fp32 transposed [n][t].
__global__ __launch_bounds__(256) void proj_k(
    const float* __restrict__ xq, const short* __restrict__ Wq,
    const float* __restrict__ bq, float* __restrict__ Qt,
    const float* __restrict__ xk, const short* __restrict__ Wk,
    const float* __restrict__ bk, float* __restrict__ Kt)
{
  const float* X; const short* Wt; const float* bias; float* Out;
  if (blockIdx.z == 0) { X = xq; Wt = Wq; bias = bq; Out = Qt; }
  else                 { X = xk; Wt = Wk; bias = bk; Out = Kt; }
  const int n0 = blockIdx.x * 64, m0 = blockIdx.y * 64;
  __shared__ __align__(16) short Ah[64 * 64];
  __shared__ __align__(16) short Al[64 * 64];
  __shared__ __align__(16) short Bh[64 * 64];
  __shared__ __align__(16) short Bl[64 * 64];
  const int tid = threadIdx.x;
  const int wave = tid >> 6, lane = tid & 63, l15 = lane & 15, kq = lane >> 4;
  const int wr = wave >> 1, wc = wave & 1;
  f32x4 acc[2][2];
#pragma unroll
  for (int i = 0; i < 2; ++i)
#pragma unroll
    for (int j = 0; j < 2; ++j)
#pragma unroll
      for (int r = 0; r < 4; ++r) acc[i][j][r] = 0.f;
  float bval[2];
#pragma unroll
  for (int j = 0; j < 2; ++j) bval[j] = bias[n0 + wc * 32 + j * 16 + l15];

  for (int s = 0; s < 16; ++s) {
    __syncthreads();
    // stage A: 64x64 fp32 -> hi/lo bf16 (512 items of 8)
#pragma unroll
    for (int l = 0; l < 2; ++l) {
      int idx = tid + l * 256;
      int row = idx >> 3, seg = idx & 7;
      const float* src = &X[(size_t)(m0 + row) * SD + s * 64 + seg * 8];
      float4 va = *(const float4*)src;
      float4 vb = *(const float4*)(src + 4);
      float xs[8] = {va.x, va.y, va.z, va.w, vb.x, vb.y, vb.z, vb.w};
      bf16x8 hi, lo;
#pragma unroll
      for (int j = 0; j < 8; ++j) {
        short hb = f2bf(xs[j]);
        hi[j] = hb; lo[j] = f2bf(xs[j] - bf2f(hb));
      }
      int dst = row * 64 + ((seg ^ (row & 7)) << 3);
      *(bf16x8*)&Ah[dst] = hi;
      *(bf16x8*)&Al[dst] = lo;
    }
    // stage B hi + lo together
#pragma unroll
    for (int l = 0; l < 2; ++l) {
      int idx = tid + l * 256;
      int row = idx >> 3, seg = idx & 7;
      int d = row * 64 + ((seg ^ (row & 7)) << 3);
      *(bf16x8*)&Bh[d] = *(const bf16x8*)&Wt[(size_t)(n0 + row) * 2048 + s * 64 + seg * 8];
      *(bf16x8*)&Bl[d] = *(const bf16x8*)&Wt[(size_t)(n0 + row) * 2048 + 1024 + s * 64 + seg * 8];
    }
    __syncthreads();
#pragma unroll
    for (int ks = 0; ks < 2; ++ks) {
      int seg = ks * 4 + kq;
      bf16x8 ah[2], al[2], bh[2], bl[2];
#pragma unroll
      for (int i = 0; i < 2; ++i) {
        int ar = wr * 32 + i * 16 + l15;
        int addr = ar * 64 + ((seg ^ (ar & 7)) << 3);
        ah[i] = *(const bf16x8*)&Ah[addr];
        al[i] = *(const bf16x8*)&Al[addr];
      }
#pragma unroll
      for (int j = 0; j < 2; ++j) {
        int br = wc * 32 + j * 16 + l15;
        int addr = br * 64 + ((seg ^ (br & 7)) << 3);
        bh[j] = *(const bf16x8*)&Bh[addr];
        bl[j] = *(const bf16x8*)&Bl[addr];
      }
#pragma unroll
      for (int i = 0; i < 2; ++i)
#pragma unroll
        for (int j = 0; j < 2; ++j) {
          acc[i][j] = __builtin_amdgcn_mfma_f32_16x16x32_bf16(ah[i], bh[j], acc[i][j], 0, 0, 0);
          acc[i][j] = __builtin_amdgcn_mfma_f32_16x16x32_bf16(al[i], bh[j], acc[i][j], 0, 0, 0);
          acc[i][j] = __builtin_amdgcn_mfma_f32_16x16x32_bf16(ah[i], bl[j], acc[i][j], 0, 0, 0);
        }
    }
  }
  // epilogue: bias, fp32 store transposed [n][t]
#pragma unroll
  for (int i = 0; i < 2; ++i)
#pragma unroll
    for (int j = 0; j < 2; ++j) {
      int n = n0 + wc * 32 + j * 16 + l15;
      int tb = m0 + wr * 32 + i * 16 + kq * 4;   // C/D row = kq*4+reg
      float4 v = make_float4(acc[i][j][0] + bval[j], acc[i][j][1] + bval[j],
                             acc[i][j][2] + bval[j], acc[i][j][3] + bval[j]);
      *(float4*)&Out[(size_t)n * SS + tb] = v;
    }
}

// ---------------- K2: packed FFT (re=q, im=k) + cross-spectrum accumulate ------
// grid (32 dgroups, 16 heads) per batch; 2 columns per block, register accum.
__global__ __launch_bounds__(256) void fftcorr_k(
    const float* __restrict__ Qt, const float* __restrict__ Kt,
    float* __restrict__ Pb, const float2* __restrict__ twtab)
{
  const int dg = blockIdx.x, h = blockIdx.y;
  __shared__ float re[2048], im[2048];
  __shared__ float twc[1024], tws[1024];
  const int tid = threadIdx.x;
  for (int j = tid; j < 1024; j += 256) {
    float2 t = twtab[j];
    twc[j] = t.x; tws[j] = t.y;
  }
  float prr[8], pii[8];
#pragma unroll
  for (int l = 0; l < 8; ++l) { prr[l] = 0.f; pii[l] = 0.f; }

  for (int dd = 0; dd < 2; ++dd) {
    const int n = h * 64 + dg * 2 + dd;
    __syncthreads();
#pragma unroll
    for (int l = 0; l < 8; ++l) {
      int t = tid + l * 256;
      int rv = __brev((unsigned)t) >> 21;
      re[rv] = Qt[(size_t)n * SS + t];
      im[rv] = Kt[(size_t)n * SS + t];
    }
    __syncthreads();
    for (int s = 1; s <= 11; ++s) {
      const int half = 1 << (s - 1);
      const int m = half << 1;
      const int tshift = 11 - s;
#pragma unroll
      for (int l = 0; l < 4; ++l) {
        int bfly = tid + l * 256;
        int g = bfly >> (s - 1), p = bfly & (half - 1);
        int i0 = g * m + p, i1 = i0 + half;
        int tj = p << tshift;
        float wr_ = twc[tj], wi_ = tws[tj];
        float xr = re[i1], xi = im[i1];
        float tr = wr_ * xr - wi_ * xi;
        float ti = wr_ * xi + wi_ * xr;
        float ur = re[i0], ui = im[i0];
        re[i1] = ur - tr; im[i1] = ui - ti;
        re[i0] = ur + tr; im[i0] = ui + ti;
      }
      __syncthreads();
    }
#pragma unroll
    for (int l = 0; l < 8; ++l) {
      int f = tid + l * 256;
      int fc = (2048 - f) & 2047;
      float Zr = re[f], Zi = im[f];
      float Zcr = re[fc], Zci = -im[fc];
      float Qr = 0.5f * (Zr + Zcr), Qi = 0.5f * (Zi + Zci);
      float Kr = 0.5f * (Zi - Zci), Ki = -0.5f * (Zr - Zcr);
      prr[l] += Qr * Kr + Qi * Ki;
      pii[l] += Qi * Kr - Qr * Ki;
    }
  }
#pragma unroll
  for (int l = 0; l < 8; ++l) {
    int f = tid + l * 256;
    atomicAdd(&Pb[((size_t)h * SS + f) * 2 + 0], prr[l]);
    atomicAdd(&Pb[((size_t)h * SS + f) * 2 + 1], pii[l]);
  }
}

// ---------------- K3: inverse FFT + byte-radix top-409 + softmax, per (b,h) ----
__global__ __launch_bounds__(256) void ifft_topk_k(
    const float* __restrict__ P, const float2* __restrict__ twtab,
    int* __restrict__ sidx, float* __restrict__ sw)
{
  const int bh = blockIdx.x;
  __shared__ float re[2048], im[2048];
  __shared__ float twc[1024], tws[1024];
  __shared__ unsigned keys[2048];
  __shared__ int el_i[KTOP];
  __shared__ float el_w[KTOP];
  __shared__ int hist[256];
  __shared__ int scan_sh[256];
  __shared__ int cnt2, tiecnt, sel_v;
  __shared__ unsigned kmax_sh;
  __shared__ float Zsh;
  const int tid = threadIdx.x;
  const float SCL = 1.0f / (2048.0f * 512.0f);   // 1/N * 1/(dh*sqrt(dh))

  for (int j = tid; j < 1024; j += 256) {
    float2 t = twtab[j];
    twc[j] = t.x; tws[j] = -t.y;   // inverse = conj of forward
  }
  if (tid == 0) { cnt2 = 0; tiecnt = 0; kmax_sh = 0u; Zsh = 0.f; }
#pragma unroll
  for (int l = 0; l < 8; ++l) {
    int f = tid + l * 256;
    int rv = __brev((unsigned)f) >> 21;
    re[rv] = P[((size_t)bh * SS + f) * 2 + 0];
    im[rv] = P[((size_t)bh * SS + f) * 2 + 1];
  }
  __syncthreads();
  for (int s = 1; s <= 11; ++s) {
    const int half = 1 << (s - 1);
    const int m = half << 1;
    const int tshift = 11 - s;
#pragma unroll
    for (int l = 0; l < 4; ++l) {
      int bfly = tid + l * 256;
      int g = bfly >> (s - 1), p = bfly & (half - 1);
      int i0 = g * m + p, i1 = i0 + half;
      int tj = p << tshift;
      float wr_ = twc[tj], wi_ = tws[tj];
      float xr = re[i1], xi = im[i1];
      float tr = wr_ * xr - wi_ * xi;
      float ti = wr_ * xi + wi_ * xr;
      float ur = re[i0], ui = im[i0];
      re[i1] = ur - tr; im[i1] = ui - ti;
      re[i0] = ur + tr; im[i0] = ui + ti;
    }
    __syncthreads();
  }
  unsigned lm = 0u;
#pragma unroll
  for (int l = 0; l < 8; ++l) {
    int i = tid + l * 256;
    float v = re[i] * SCL;
    re[i] = v;
    unsigned u = __float_as_uint(v);
    unsigned k = (u & 0x80000000u) ? ~u : (u | 0x80000000u);
    keys[i] = k;
    lm = max(lm, k);
  }
  atomicMax(&kmax_sh, lm);
  __syncthreads();

  unsigned prefix = 0u;
  int remaining = KTOP;
  for (int p = 3; p >= 0; --p) {
    hist[tid] = 0;
    __syncthreads();
    unsigned mask_hi = (p == 3) ? 0u : (0xFFFFFFFFu << ((p + 1) * 8));
#pragma unroll
    for (int l = 0; l < 8; ++l) {
      unsigned k = keys[tid + l * 256];
      if ((k & mask_hi) == prefix) atomicAdd(&hist[(k >> (p * 8)) & 255], 1);
    }
    __syncthreads();
    scan_sh[tid] = hist[tid];
    __syncthreads();
    for (int off = 1; off < 256; off <<= 1) {
      int add = (tid + off < 256) ? scan_sh[tid + off] : 0;
      __syncthreads();
      scan_sh[tid] += add;
      __syncthreads();
    }
    if (scan_sh[tid] >= remaining && (tid == 255 || scan_sh[tid + 1] < remaining))
      sel_v = tid;
    __syncthreads();
    int v = sel_v;
    int above = (v == 255) ? 0 : scan_sh[v + 1];
    remaining -= above;
    prefix |= ((unsigned)v) << (p * 8);
    __syncthreads();
  }
  const unsigned T = prefix;
  unsigned km = kmax_sh;
  float vmax = __uint_as_float((km & 0x80000000u) ? (km ^ 0x80000000u) : ~km);

#pragma unroll
  for (int l = 0; l < 8; ++l) {
    int i = tid + l * 256;
    unsigned k = keys[i];
    if (k > T) {
      int pos = atomicAdd(&cnt2, 1);
      el_i[pos] = i;
      el_w[pos] = expf(re[i] - vmax);
    } else if (k == T) {
      atomicAdd(&tiecnt, 1);
    }
  }
  __syncthreads();
  int need = KTOP - cnt2;
  if (tiecnt == need) {
#pragma unroll
    for (int l = 0; l < 8; ++l) {
      int i = tid + l * 256;
      if (keys[i] == T) {
        int pos = atomicAdd(&cnt2, 1);
        el_i[pos] = i;
        el_w[pos] = expf(re[i] - vmax);
      }
    }
  } else if (tid == 0) {
    int pos = cnt2;
    for (int i = 0; i < SS && pos < KTOP; ++i)
      if (keys[i] == T) { el_i[pos] = i; el_w[pos] = expf(re[i] - vmax); ++pos; }
  }
  __syncthreads();
  float z = 0.f;
  for (int l = tid; l < KTOP; l += 256) z += el_w[l];
  atomicAdd(&Zsh, z);
  __syncthreads();
  float invZ = 1.0f / Zsh;
  for (int l = tid; l < KTOP; l += 256) {
    sidx[bh * KTOP + l] = el_i[l];
    sw[bh * KTOP + l]   = el_w[l] * invZ;
  }
}

// ---------------- K4: xbar[b,h,:] = sum_sel w * xv[b,idx,:] --------------------
__global__ __launch_bounds__(256) void xbar_k(
    const int* __restrict__ sidx, const float* __restrict__ sw,
    const float* __restrict__ xv, float* __restrict__ xbar)
{
  const int bh = blockIdx.x, b = bh >> 4;
  __shared__ int il[KTOP];
  __shared__ float wl[KTOP];
  const int tid = threadIdx.x;
  for (int l = tid; l < KTOP; l += 256) { il[l] = sidx[bh * KTOP + l]; wl[l] = sw[bh * KTOP + l]; }
  __syncthreads();
  const float4* xv4 = (const float4*)xv;
  float4 acc = make_float4(0.f, 0.f, 0.f, 0.f);
  for (int r = 0; r < KTOP; ++r) {
    float w = wl[r];
    float4 v = xv4[(size_t)(b * SS + il[r]) * 256 + tid];
    acc.x += w * v.x; acc.y += w * v.y; acc.z += w * v.z; acc.w += w * v.w;
  }
  ((float4*)xbar)[(size_t)bh * 256 + tid] = acc;
}

// ---------------- K5a: init attended=bv, outrow=bo -----------------------------
__global__ __launch_bounds__(256) void initbias_k(
    const float* __restrict__ bv, const float* __restrict__ bo,
    float* __restrict__ att, float* __restrict__ orow)
{
  int i = blockIdx.x * 256 + threadIdx.x;   // < 8192
  if (i < 4096) att[i] = bv[i & 1023];
  else          orow[i - 4096] = bo[i & 1023];
}

// ---------------- K5: attended[b,j] += sum_i xbar[b,j/64,i]*wv[i,j] ------------
__global__ __launch_bounds__(256) void attend_k(
    const float* __restrict__ xbar, const float* __restrict__ wv,
    float* __restrict__ att)
{
  const int b = blockIdx.y, i0 = blockIdx.x * 64;
  __shared__ float xs[16 * 64];
  const int tid = threadIdx.x;
#pragma unroll
  for (int l = 0; l < 4; ++l) {
    int f = tid + l * 256;
    xs[f] = xbar[(size_t)(b * 16 + (f >> 6)) * 1024 + i0 + (f & 63)];
  }
  __syncthreads();
  const float4* wv4 = (const float4*)wv;
  const int h = tid >> 4;
  float4 acc = make_float4(0.f, 0.f, 0.f, 0.f);
  for (int m = 0; m < 64; ++m) {
    float xvs = xs[h * 64 + m];
    float4 w = wv4[(size_t)(i0 + m) * 256 + tid];
    acc.x += xvs * w.x; acc.y += xvs * w.y; acc.z += xvs * w.z; acc.w += xvs * w.w;
  }
  float* dst = att + (size_t)b * 1024 + tid * 4;
  atomicAdd(dst + 0, acc.x); atomicAdd(dst + 1, acc.y);
  atomicAdd(dst + 2, acc.z); atomicAdd(dst + 3, acc.w);
}

// ---------------- K6: outrow[b,n] += sum_m att[b,m]*wo[m,n] --------------------
__global__ __launch_bounds__(256) void oproj_k(
    const float* __restrict__ att, const float* __restrict__ wo,
    float* __restrict__ orow)
{
  const int b = blockIdx.y, m0 = blockIdx.x * 64;
  __shared__ float as_[64];
  const int tid = threadIdx.x;
  if (tid < 64) as_[tid] = att[(size_t)b * 1024 + m0 + tid];
  __syncthreads();
  const float4* wo4 = (const float4*)wo;
  float4 acc = make_float4(0.f, 0.f, 0.f, 0.f);
  for (int m = 0; m < 64; ++m) {
    float a = as_[m];
    float4 w = wo4[(size_t)(m0 + m) * 256 + tid];
    acc.x += a * w.x; acc.y += a * w.y; acc.z += a * w.z; acc.w += a * w.w;
  }
  float* dst = orow + (size_t)b * 1024 + tid * 4;
  atomicAdd(dst + 0, acc.x); atomicAdd(dst + 1, acc.y);
  atomicAdd(dst + 2, acc.z); atomicAdd(dst + 3, acc.w);
}

// ---------------- K7: broadcast outrow across S --------------------------------
__global__ __launch_bounds__(256) void bcast_k(
    const float* __restrict__ orow, float* __restrict__ out)
{
  int idx = blockIdx.x * 256 + threadIdx.x;           // float4 index
  const float4* o4 = (const float4*)orow;
  ((float4*)out)[idx] = o4[((idx >> 19) << 8) | (idx & 255)];
}

extern "C" void kernel_launch(void* const* d_in, const int* in_sizes, int n_in,
                              void* d_out, int out_size, void* d_ws, size_t ws_size,
                              hipStream_t stream) {
  (void)in_sizes; (void)n_in; (void)out_size; (void)ws_size;
  const float* xq = (const float*)d_in[0];
  const float* xk = (const float*)d_in[1];
  const float* xv = (const float*)d_in[2];
  const float* wq = (const float*)d_in[3];
  const float* bq = (const float*)d_in[4];
  const float* wk = (const float*)d_in[5];
  const float* bk = (const float*)d_in[6];
  const float* wv = (const float*)d_in[7];
  const float* bv = (const float*)d_in[8];
  const float* wo = (const float*)d_in[9];
  const float* bo = (const float*)d_in[10];
  float* out = (float*)d_out;

  // ---- scratch in d_out (32 MB; all dead before bcast_k overwrites it) ----
  char* ob = (char*)d_out;
  float* Qt  = (float*)(ob);                   // 8 MB  [n][t] fp32
  float* Kt  = (float*)(ob + ( 8u << 20));     // 8 MB
  short* Wqt = (short*)(ob + (16u << 20));     // 4 MB
  short* Wkt = (short*)(ob + (20u << 20));     // 4 MB (24..32 MB unused)

  // ---- d_ws: ~2 MB ----
  char* base = (char*)d_ws;
  float* P = (float*)base;                     // B*H*S complex = 1 MB
  size_t off = (size_t)SB * SH * SS * 2 * 4;
  float2* twtab = (float2*)(base + off); off += 1024 * 8;
  int*   sidx = (int*)  (base + off); off += (size_t)SB * SH * KTOP * 4;
  float* sw   = (float*)(base + off); off += (size_t)SB * SH * KTOP * 4;
  float* xbar = (float*)(base + off); off += (size_t)SB * SH * SD * 4;
  float* att  = (float*)(base + off); off += (size_t)SB * SD * 4;
  float* orow = (float*)(base + off);

  twiddle_k<<<dim3(4), 256, 0, stream>>>(twtab);
  splitwt_k<<<dim3(16, 16, 2), 256, 0, stream>>>(wq, wk, Wqt, Wkt);
  hipMemsetAsync(P, 0, (size_t)SB * SH * SS * 2 * sizeof(float), stream);

  for (int b = 0; b < SB; ++b) {
    proj_k<<<dim3(16, 32, 2), 256, 0, stream>>>(
        xq + (size_t)b * SS * SD, Wqt, bq, Qt,
        xk + (size_t)b * SS * SD, Wkt, bk, Kt);
    fftcorr_k<<<dim3(32, 16), 256, 0, stream>>>(
        Qt, Kt, P + (size_t)b * SH * SS * 2, twtab);
  }
  ifft_topk_k<<<dim3(SB * SH), 256, 0, stream>>>(P, twtab, sidx, sw);
  xbar_k<<<dim3(SB * SH), 256, 0, stream>>>(sidx, sw, xv, xbar);
  initbias_k<<<dim3(32), 256, 0, stream>>>(bv, bo, att, orow);
  attend_k<<<dim3(16, SB), 256, 0, stream>>>(xbar, wv, att);
  oproj_k<<<dim3(16, SB), 256, 0, stream>>>(att, wo, orow);
  bcast_k<<<dim3(8192), 256, 0, stream>>>(orow, out);
}